// Round 6
// baseline (178.197 us; speedup 1.0000x reference)
//
#include <hip/hip_runtime.h>
#include <math.h>

// Dims: B=1,V=16,T=1,F=1 -> fv=16; N=12288, n=16, K=9, ATT=128, NH=4, H=32, NA=4.
// All float tensors FP32 on device. 64 tokens (16 fields x 4 nodes) per group.
//
// Swapped-operand MFMA scheme (token on B/n, feature on A/m) -> packed b64 C-writes,
// in-lane softmax/LN. This round: NO LDS stage (direct global A-fragments from xt),
// padded LDS strides (272/136/144 = 16 mod 128) instead of XOR swizzle -> conflict-free,
// single __syncthreads per block.
#define NNODE 12288
#define XSTRIDE 196608
#define NGRP 3072
#define XT_ELEMS 3145728        // 12288*256 bf16 LN1'd tokens [node][v][ch]
#define WS_WQT   0              // WqT[128][32]  (K-pad 16->32)
#define WS_WKVT  4096           // WkvT[256][160] (K-pad 144->160)
#define WS_WOUTT 45056          // WoutT[16][128]
#define WS_W1T   47104          // W1T[32][32]   (K-pad 16->32)
#define WS_W2T   48128          // W2T[16][32]
#define WS_WTOT  48640
#define WS_BYTES ((size_t)(XT_ELEMS + WS_WTOT) * 2)

// LDS: kbuf [64 tok][272B] | vtb [128 dim][136B] | 4 wave slots [16][272B] (h/hid overlay @144B)
#define KBUF_OFF 0
#define VTB_OFF  17408
#define QSL_OFF  34816
#define LDS_TOTAL 53248         // 52 KB -> 3 blocks/CU

typedef unsigned short u16;
typedef short short8 __attribute__((ext_vector_type(8)));
typedef float f32x4 __attribute__((ext_vector_type(4)));

#define MFMA16(a,b,c) __builtin_amdgcn_mfma_f32_16x16x32_bf16((a),(b),(c),0,0,0)

__device__ __forceinline__ u16 f2b(float f) {   // f32->bf16 RNE
  unsigned u = __float_as_uint(f);
  return (u16)((u + 0x7FFFu + ((u >> 16) & 1u)) >> 16);
}
__device__ __forceinline__ unsigned pk2(float a, float b) {  // 2xf32 -> packed bf16 (RTZ)
  return (__float_as_uint(a) >> 16) | (__float_as_uint(b) & 0xFFFF0000u);
}
__device__ __forceinline__ float gelu_fast(float v) {
  float u = v * (1.0f + 0.044715f * v * v);
  float e = __expf(-1.5957691216057308f * u);
  return v / (1.0f + e);
}
#define DS_FENCE() do { asm volatile("s_waitcnt lgkmcnt(0)" ::: "memory"); \
                        __builtin_amdgcn_sched_barrier(0); } while (0)

// in-lane softmax over 16 values + cross-kgrp shfl; returns 1/sum, s4 <- exp((s-max)/sqrt(32))
__device__ __forceinline__ float softmax16(f32x4 s4[4]) {
  const float C2 = 0.25508682300212037f;  // log2(e)/sqrt(32)
  f32x4 m01, m23;
  #pragma unroll
  for (int r = 0; r < 4; ++r) { m01[r] = fmaxf(s4[0][r], s4[1][r]); m23[r] = fmaxf(s4[2][r], s4[3][r]); }
  float mx = fmaxf(fmaxf(fmaxf(m01[0], m23[0]), fmaxf(m01[1], m23[1])),
                   fmaxf(fmaxf(m01[2], m23[2]), fmaxf(m01[3], m23[3])));
  mx = fmaxf(mx, __shfl_xor(mx, 16));
  mx = fmaxf(mx, __shfl_xor(mx, 32));
  float nmx = mx * C2;
  float sum = 0.f;
  #pragma unroll
  for (int mt = 0; mt < 4; ++mt)
    #pragma unroll
    for (int r = 0; r < 4; ++r) {
      float e = exp2f(__builtin_fmaf(s4[mt][r], C2, -nmx));
      s4[mt][r] = e; sum += e;
    }
  sum += __shfl_xor(sum, 16);
  sum += __shfl_xor(sum, 32);
  return 1.0f / sum;
}

// ---------- ln1x (blocks 0..767, LDS-transposed coalesced) + weight prep (768..957) ----
__global__ __launch_bounds__(256)
void ln1x_prep(const float* __restrict__ x, const float* __restrict__ ln1s,
               const float* __restrict__ ln1b,
               const float* __restrict__ Wq, const float* __restrict__ Wkv,
               const float* __restrict__ Wout, const float* __restrict__ W1,
               const float* __restrict__ W2, u16* __restrict__ ws)
{
  const int t = threadIdx.x;
  if (blockIdx.x >= 768) {
    int i = (blockIdx.x - 768) * 256 + t;
    if (i >= WS_WTOT) return;
    u16* wbase = ws + XT_ELEMS;
    int j = i;
    if (j < 4096)  { int n = j >> 5, k = j & 31;   wbase[WS_WQT   + j] = f2b(k < 16  ? Wq[k * 128 + n]  : 0.f); return; }
    j -= 4096;
    if (j < 40960) { int n = j / 160, k = j % 160; wbase[WS_WKVT  + j] = f2b(k < 144 ? Wkv[k * 256 + n] : 0.f); return; }
    j -= 40960;
    if (j < 2048)  { int n = j >> 7, k = j & 127;  wbase[WS_WOUTT + j] = f2b(Wout[k * 16 + n]); return; }
    j -= 2048;
    if (j < 1024)  { int n = j >> 5, k = j & 31;   wbase[WS_W1T   + j] = f2b(k < 16 ? W1[k * 32 + n] : 0.f); return; }
    j -= 1024;
    { int n = j >> 5, k = j & 31; wbase[WS_W2T + j] = f2b(W2[k * 16 + n]); }
    return;
  }
  __shared__ u16 buf[4096];
  const int node0 = blockIdx.x * 16;
  const int v = t >> 4, nd = t & 15;
  const f32x4* xp = (const f32x4*)(x + (size_t)v * XSTRIDE + (node0 + nd) * 16);
  f32x4 p0 = xp[0], p1 = xp[1], p2 = xp[2], p3 = xp[3];
  float va[16] = {p0[0],p0[1],p0[2],p0[3], p1[0],p1[1],p1[2],p1[3],
                  p2[0],p2[1],p2[2],p2[3], p3[0],p3[1],p3[2],p3[3]};
  float s = 0.f, ss = 0.f;
  #pragma unroll
  for (int j = 0; j < 16; ++j) { s += va[j]; ss += va[j] * va[j]; }
  float mean = s * 0.0625f, rs = rsqrtf(ss * 0.0625f - mean * mean + 1e-5f);
  short8 o0, o1;
  #pragma unroll
  for (int j = 0; j < 8; ++j) {
    o0[j] = (short)f2b((va[j]     - mean) * rs * ln1s[j]     + ln1b[j]);
    o1[j] = (short)f2b((va[j + 8] - mean) * rs * ln1s[j + 8] + ln1b[j + 8]);
  }
  *(short8*)(buf + nd * 256 + v * 16)     = o0;
  *(short8*)(buf + nd * 256 + v * 16 + 8) = o1;
  __syncthreads();
  const short8* src = (const short8*)(buf + t * 16);
  short8* dst = (short8*)(ws + node0 * 256 + t * 16);
  dst[0] = src[0]; dst[1] = src[1];
}

// ---------- main fused kernel: one block per attention group ----------
__global__ __launch_bounds__(256, 3)
void mfa_main(const float* __restrict__ x, const int* __restrict__ adjc,
              const float* __restrict__ bkv, const float* __restrict__ bout,
              const float* __restrict__ gamma, const float* __restrict__ ln2s,
              const float* __restrict__ ln2b, const float* __restrict__ b1,
              const float* __restrict__ b2, const float* __restrict__ gmlp,
              const u16* __restrict__ ws, float* __restrict__ y)
{
  __shared__ __align__(16) unsigned char smem[LDS_TOTAL];
  const int t = threadIdx.x, g = blockIdx.x;
  const int w = t >> 6, lrow = t & 15, kgrp = (t >> 4) & 3, k0 = kgrp * 8;

  char* kbuf = (char*)(smem + KBUF_OFF);            // [64 tok][272B] k (bf16 ch)
  char* vtb  = (char*)(smem + VTB_OFF);             // [128 dim][136B] vT (bf16 tok)
  char* qsl  = (char*)(smem + QSL_OFF + w * 4608);  // wave slot: qp/P/O [16][272B]; h/hid @144B stride

  const u16* xt = ws;
  const u16* wb = ws + XT_ELEMS;
  const f32x4 z4 = {0.f, 0.f, 0.f, 0.f};
  const short8 z8 = {0,0,0,0,0,0,0,0};

  // ======== Phase A: early loads + qproj ========
  const int tok = w * 16 + lrow, tv = tok >> 2, tnode = g * 4 + (lrow & 3);
  // own-node adjacency row (9 ints, contiguous)
  const int* arow = adjc + tnode * 9;
  int4 a03 = *(const int4*)(arow);
  int4 a47 = *(const int4*)(arow + 4);
  int  a8  = arow[8];
  short8 qbx = (kgrp < 2) ? *(const short8*)(xt + tnode * 256 + tv * 16 + k0) : z8;

  // qproj (swapped): D(m=feat 4kgrp+r, n=token lrow) -> packed b64 into qsl rows
  #pragma unroll
  for (int ft = 0; ft < 8; ++ft) {
    short8 wA = *(const short8*)(wb + WS_WQT + (ft * 16 + lrow) * 32 + k0);
    f32x4 c = MFMA16(wA, qbx, z4);
    *(uint2*)(qsl + lrow * 272 + 32 * ft + 8 * kgrp) =
        make_uint2(pk2(c[0], c[1]), pk2(c[2], c[3]));
  }

  // ======== Phase B: kvproj [64 tok][160K] -> k + vT, A-fragments direct from xt ========
  f32x4 acc[4][4];   // [c: 2 k-tiles + 2 v-tiles][mt]
  #pragma unroll
  for (int c = 0; c < 4; ++c)
    #pragma unroll
    for (int mt = 0; mt < 4; ++mt) acc[c][mt] = z4;
  const int ctk = 2 * w, ctv = 8 + 2 * w;
  const int hi = kgrp >> 1, hlo = (kgrp & 1) * 8;
  #pragma unroll
  for (int kc = 0; kc < 5; ++kc) {
    // neighbor for this lane's K-slice: nbr = 2*kc + hi  (nbr 9 = zero pad)
    int an;
    if      (kc == 0) an = hi ? a03.y : a03.x;
    else if (kc == 1) an = hi ? a03.w : a03.z;
    else if (kc == 2) an = hi ? a47.y : a47.x;
    else if (kc == 3) an = hi ? a47.w : a47.z;
    else              an = a8;                    // kc==4: nbr 8 (hi==1 is dead pad)
    const bool dead = (kc == 4) && (hi == 1);
    short8 tf[4], wf[4];
    #pragma unroll
    for (int mt = 0; mt < 4; ++mt) {
      int vv = mt * 4 + (lrow >> 2);
      short8 ld = *(const short8*)(xt + an * 256 + vv * 16 + hlo);
      tf[mt] = dead ? z8 : ld;
    }
    wf[0] = *(const short8*)(wb + WS_WKVT + ((ctk    ) * 16 + lrow) * 160 + kc * 32 + k0);
    wf[1] = *(const short8*)(wb + WS_WKVT + ((ctk + 1) * 16 + lrow) * 160 + kc * 32 + k0);
    wf[2] = *(const short8*)(wb + WS_WKVT + ((ctv    ) * 16 + lrow) * 160 + kc * 32 + k0);
    wf[3] = *(const short8*)(wb + WS_WKVT + ((ctv + 1) * 16 + lrow) * 160 + kc * 32 + k0);
    #pragma unroll
    for (int mt = 0; mt < 4; ++mt) {
      acc[0][mt] = MFMA16(wf[0], tf[mt], acc[0][mt]);   // k: D(m=ch, n=tok)
      acc[1][mt] = MFMA16(wf[1], tf[mt], acc[1][mt]);
      acc[2][mt] = MFMA16(tf[mt], wf[2], acc[2][mt]);   // v: D(m=tok, n=ch)
      acc[3][mt] = MFMA16(tf[mt], wf[3], acc[3][mt]);
    }
  }
  #pragma unroll
  for (int c = 0; c < 2; ++c) {        // k-half: token rows, 4 consecutive ch packed
    const int ct = ctk + c;
    f32x4 bk = *(const f32x4*)(bkv + ct * 16 + 4 * kgrp);
    #pragma unroll
    for (int mt = 0; mt < 4; ++mt) {
      f32x4 a = acc[c][mt];
      *(uint2*)(kbuf + (mt * 16 + lrow) * 272 + 32 * ct + 8 * kgrp) =
          make_uint2(pk2(a[0] + bk[0], a[1] + bk[1]), pk2(a[2] + bk[2], a[3] + bk[3]));
    }
  }
  #pragma unroll
  for (int c = 0; c < 2; ++c) {        // v-half: dim rows, 4 consecutive tokens packed
    const int vc = (2 * w + c) * 16 + lrow;
    float bv = bkv[128 + vc];
    #pragma unroll
    for (int mt = 0; mt < 4; ++mt) {
      f32x4 a = acc[2 + c][mt];
      *(uint2*)(vtb + vc * 136 + 32 * mt + 8 * kgrp) =
          make_uint2(pk2(a[0] + bv, a[1] + bv), pk2(a[2] + bv, a[3] + bv));
    }
  }
  __syncthreads();   // THE barrier: k/vT (cross-wave) + own qp visible

  // ======== Phase C: per-head S^T -> in-lane softmax -> PV (O^T), head pairs ========
  short8 qbh0 = *(const short8*)(qsl + lrow * 272 +   0 + 16 * kgrp);
  short8 qbh1 = *(const short8*)(qsl + lrow * 272 +  64 + 16 * kgrp);
  short8 qbh2 = z8, qbh3 = z8;
  f32x4 oacc[4][2];
  float invh[4];
  #pragma unroll
  for (int h = 0; h < 4; ++h) { oacc[h][0] = z4; oacc[h][1] = z4; }

  #pragma unroll
  for (int hp = 0; hp < 2; ++hp) {
    const int h0 = 2 * hp, h1 = h0 + 1;
    f32x4 s4a[4], s4b[4];
    #pragma unroll
    for (int mt = 0; mt < 4; ++mt) {
      short8 ka = *(const short8*)(kbuf + (mt * 16 + lrow) * 272 + 64 * h0 + 16 * kgrp);
      s4a[mt] = MFMA16(ka, hp ? qbh2 : qbh0, z4);   // D(m=kv, n=q)
    }
    #pragma unroll
    for (int mt = 0; mt < 4; ++mt) {
      short8 kb = *(const short8*)(kbuf + (mt * 16 + lrow) * 272 + 64 * h1 + 16 * kgrp);
      s4b[mt] = MFMA16(kb, hp ? qbh3 : qbh1, z4);
    }
    if (hp == 0) {   // prefetch Q for heads 2,3 before P overwrites qp rows
      qbh2 = *(const short8*)(qsl + lrow * 272 + 128 + 16 * kgrp);
      qbh3 = *(const short8*)(qsl + lrow * 272 + 192 + 16 * kgrp);
    }
    invh[h0] = softmax16(s4a);
    invh[h1] = softmax16(s4b);
    #pragma unroll
    for (int mt = 0; mt < 4; ++mt) {   // P (unnormalized) packed into qp rows
      *(uint2*)(qsl + lrow * 272 +       32 * mt + 8 * kgrp) =
          make_uint2(pk2(s4a[mt][0], s4a[mt][1]), pk2(s4a[mt][2], s4a[mt][3]));
      *(uint2*)(qsl + lrow * 272 + 128 + 32 * mt + 8 * kgrp) =
          make_uint2(pk2(s4b[mt][0], s4b[mt][1]), pk2(s4b[mt][2], s4b[mt][3]));
    }
    DS_FENCE();
    #pragma unroll
    for (int hh = 0; hh < 2; ++hh) {
      const int h = 2 * hp + hh;
      #pragma unroll
      for (int kc = 0; kc < 2; ++kc) {
        short8 pB = *(const short8*)(qsl + lrow * 272 + 128 * hh + 64 * kc + 16 * kgrp);
        #pragma unroll
        for (int nt = 0; nt < 2; ++nt) {
          short8 vA = *(const short8*)(vtb + (h * 32 + nt * 16 + lrow) * 136 + 64 * kc + 16 * kgrp);
          oacc[h][nt] = MFMA16(vA, pB, oacc[h][nt]);   // O^T: D(m=dim, n=q)
        }
      }
    }
  }

  // params + residual (latency hidden under O-pack/fence)
  f32x4 p_gam = *(const f32x4*)(gamma + 4 * kgrp);
  f32x4 p_bo  = *(const f32x4*)(bout  + 4 * kgrp);
  f32x4 p_l2s = *(const f32x4*)(ln2s  + 4 * kgrp);
  f32x4 p_l2b = *(const f32x4*)(ln2b  + 4 * kgrp);
  f32x4 p_b1a = *(const f32x4*)(b1 + 4 * kgrp);
  f32x4 p_b1b = *(const f32x4*)(b1 + 16 + 4 * kgrp);
  f32x4 p_b2  = *(const f32x4*)(b2   + 4 * kgrp);
  f32x4 p_gm2 = *(const f32x4*)(gmlp + 4 * kgrp);
  f32x4 xr = *(const f32x4*)(x + (size_t)tv * XSTRIDE + tnode * 16 + 4 * kgrp);

  // O (normalized) -> qp rows, packed
  #pragma unroll
  for (int h = 0; h < 4; ++h) {
    float iv = invh[h];
    #pragma unroll
    for (int nt = 0; nt < 2; ++nt) {
      f32x4 a = oacc[h][nt];
      *(uint2*)(qsl + lrow * 272 + 64 * h + 32 * nt + 8 * kgrp) =
          make_uint2(pk2(a[0] * iv, a[1] * iv), pk2(a[2] * iv, a[3] * iv));
    }
  }
  DS_FENCE();

  // ======== Phase D: outproj + LN2 + MLP (wave-local) ========
  f32x4 oc = z4;
  #pragma unroll
  for (int kc = 0; kc < 4; ++kc) {
    short8 oB = *(const short8*)(qsl + lrow * 272 + 64 * kc + 16 * kgrp);
    short8 wo = *(const short8*)(wb + WS_WOUTT + lrow * 128 + kc * 32 + k0);
    oc = MFMA16(wo, oB, oc);   // D(m=ch, n=token)
  }
  float xov[4]; float s = 0.f, ss = 0.f;
  #pragma unroll
  for (int r = 0; r < 4; ++r) {
    xov[r] = xr[r] + p_gam[r] * (oc[r] + p_bo[r]);
    s += xov[r]; ss += xov[r] * xov[r];
  }
  s  += __shfl_xor(s, 16);  s  += __shfl_xor(s, 32);
  ss += __shfl_xor(ss, 16); ss += __shfl_xor(ss, 32);
  float mean = s * 0.0625f, rstd = rsqrtf(ss * 0.0625f - mean * mean + 1e-5f);
  float hv[4];
  #pragma unroll
  for (int r = 0; r < 4; ++r) hv[r] = (xov[r] - mean) * rstd * p_l2s[r] + p_l2b[r];
  // h [16 tok][32ch pad] @144B stride (overlays O region; in-order DS pipe)
  *(uint2*)(qsl + lrow * 144 + 8 * kgrp)      = make_uint2(pk2(hv[0], hv[1]), pk2(hv[2], hv[3]));
  *(uint2*)(qsl + lrow * 144 + 32 + 8 * kgrp) = make_uint2(0u, 0u);   // K-pad ch 16..31
  DS_FENCE();
  short8 hB = *(const short8*)(qsl + lrow * 144 + 16 * kgrp);
  float hid[8];
  #pragma unroll
  for (int ft = 0; ft < 2; ++ft) {
    short8 w1 = *(const short8*)(wb + WS_W1T + (ft * 16 + lrow) * 32 + k0);
    f32x4 hc = MFMA16(w1, hB, z4);    // D(m=hch, n=token)
    f32x4 bb = ft ? p_b1b : p_b1a;
    #pragma unroll
    for (int r = 0; r < 4; ++r) hid[ft * 4 + r] = gelu_fast(hc[r] + bb[r]);
  }
  *(uint2*)(qsl + lrow * 144 + 72 + 8 * kgrp)      = make_uint2(pk2(hid[0], hid[1]), pk2(hid[2], hid[3]));
  *(uint2*)(qsl + lrow * 144 + 72 + 32 + 8 * kgrp) = make_uint2(pk2(hid[4], hid[5]), pk2(hid[6], hid[7]));
  DS_FENCE();
  short8 hidB = *(const short8*)(qsl + lrow * 144 + 72 + 16 * kgrp);
  short8 w2 = *(const short8*)(wb + WS_W2T + lrow * 32 + k0);
  f32x4 mc = MFMA16(w2, hidB, z4);    // D(m=out-ch, n=token)
  f32x4 yv;
  #pragma unroll
  for (int r = 0; r < 4; ++r) yv[r] = xov[r] + p_gm2[r] * (mc[r] + p_b2[r]);
  *(f32x4*)(y + (size_t)tv * XSTRIDE + tnode * 16 + 4 * kgrp) = yv;
}

extern "C" void kernel_launch(void* const* d_in, const int* in_sizes, int n_in,
                              void* d_out, int out_size, void* d_ws, size_t ws_size,
                              hipStream_t stream) {
  const float* x    = (const float*)d_in[0];
  const int*   adjc = (const int*)  d_in[1];
  const float* ln1s = (const float*)d_in[2];
  const float* ln1b = (const float*)d_in[3];
  const float* Wq   = (const float*)d_in[4];
  const float* Wkv  = (const float*)d_in[5];
  const float* bkv  = (const float*)d_in[6];
  const float* Wout = (const float*)d_in[7];
  const float* bout = (const float*)d_in[8];
  const float* gam  = (const float*)d_in[9];
  const float* ln2s = (const float*)d_in[10];
  const float* ln2b = (const float*)d_in[11];
  const float* W1   = (const float*)d_in[12];
  const float* b1   = (const float*)d_in[13];
  const float* W2   = (const float*)d_in[14];
  const float* b2   = (const float*)d_in[15];
  const float* gmlp = (const float*)d_in[16];
  float* y = (float*)d_out;
  u16* ws = (u16*)d_ws;
  if (ws_size < WS_BYTES) return;   // needs ~6.4 MB scratch

  ln1x_prep<<<958, 256, 0, stream>>>(x, ln1s, ln1b, Wq, Wkv, Wout, W1, W2, ws);
  mfa_main<<<NGRP, 256, 0, stream>>>(x, adjc, bkv, bout, gam, ln2s, ln2b,
                                     b1, b2, gmlp, ws, y);
}

// Round 7
// 168.969 us; speedup vs baseline: 1.0546x; 1.0546x over previous
//
#include <hip/hip_runtime.h>
#include <math.h>

// Dims: B=1,V=16,T=1,F=1 -> fv=16; N=12288, n=16, K=9, ATT=128, NH=4, H=32, NA=4.
// FP32 I/O. 64 tokens per group, re-labeled tau = node_in_group*16 + field
// (attention is permutation-invariant over the window; this makes every LDS
// row-stride an odd multiple of 16B -> conflict-free, and tnode wave-uniform).
#define NNODE 12288
#define XSTRIDE 196608
#define NGRP 3072
#define XT_ELEMS 3145728        // 12288*256 bf16 LN1'd tokens [node][v][ch]
#define WS_WQT   0              // WqT[128][32]  (K-pad 16->32)
#define WS_WKVT  4096           // WkvT[256][160] (K-pad 144->160)
#define WS_WOUTT 45056          // WoutT[16][128]
#define WS_W1T   47104          // W1T[32][32]   (K-pad 16->32)
#define WS_W2T   48128          // W2T[16][32]
#define WS_WTOT  48640
#define WS_BYTES ((size_t)(XT_ELEMS + WS_WTOT) * 2)

// LDS: stage [64][336] overlays (kbuf [64][272] + vtb [128][144]); qsl 4x4608
#define S_STAGE 336
#define S_K     272
#define S_VT    144
#define S_Q     272
#define KBUF_OFF 0
#define VTB_OFF  17408          // 64*272
#define QSL_OFF  35840          // VTB_OFF + 128*144
#define QSL_SLOT 4608           // qp/P/O rows 16*272=4352; h @0, hid @2304 (stride 144)
#define LDS_TOTAL 54272         // 3 blocks/CU: 3*54272 = 162816 <= 163840

typedef unsigned short u16;
typedef short short8 __attribute__((ext_vector_type(8)));
typedef float f32x4 __attribute__((ext_vector_type(4)));

#define MFMA16(a,b,c) __builtin_amdgcn_mfma_f32_16x16x32_bf16((a),(b),(c),0,0,0)

__device__ __forceinline__ u16 f2b(float f) {   // f32->bf16 RNE
  unsigned u = __float_as_uint(f);
  return (u16)((u + 0x7FFFu + ((u >> 16) & 1u)) >> 16);
}
__device__ __forceinline__ unsigned pk2(float a, float b) {  // 2xf32 -> packed bf16 (RTZ)
  return (__float_as_uint(a) >> 16) | (__float_as_uint(b) & 0xFFFF0000u);
}
__device__ __forceinline__ float gelu_fast(float v) {
  float u = v * (1.0f + 0.044715f * v * v);
  float e = __expf(-1.5957691216057308f * u);
  return v / (1.0f + e);
}
#define DS_FENCE() do { asm volatile("s_waitcnt lgkmcnt(0)" ::: "memory"); \
                        __builtin_amdgcn_sched_barrier(0); } while (0)

// in-lane softmax over 16 values + cross-kgrp shfl; returns 1/sum, s4 <- exp((s-max)/sqrt(32))
__device__ __forceinline__ float softmax16(f32x4 s4[4]) {
  const float C2 = 0.25508682300212037f;  // log2(e)/sqrt(32)
  f32x4 m01, m23;
  #pragma unroll
  for (int r = 0; r < 4; ++r) { m01[r] = fmaxf(s4[0][r], s4[1][r]); m23[r] = fmaxf(s4[2][r], s4[3][r]); }
  float mx = fmaxf(fmaxf(fmaxf(m01[0], m23[0]), fmaxf(m01[1], m23[1])),
                   fmaxf(fmaxf(m01[2], m23[2]), fmaxf(m01[3], m23[3])));
  mx = fmaxf(mx, __shfl_xor(mx, 16));
  mx = fmaxf(mx, __shfl_xor(mx, 32));
  float nmx = mx * C2;
  float sum = 0.f;
  #pragma unroll
  for (int mt = 0; mt < 4; ++mt)
    #pragma unroll
    for (int r = 0; r < 4; ++r) {
      float e = exp2f(__builtin_fmaf(s4[mt][r], C2, -nmx));
      s4[mt][r] = e; sum += e;
    }
  sum += __shfl_xor(sum, 16);
  sum += __shfl_xor(sum, 32);
  return 1.0f / sum;
}

// ---------- ln1x (blocks 0..767, LDS-transposed coalesced) + weight prep (768..957) ----
__global__ __launch_bounds__(256)
void ln1x_prep(const float* __restrict__ x, const float* __restrict__ ln1s,
               const float* __restrict__ ln1b,
               const float* __restrict__ Wq, const float* __restrict__ Wkv,
               const float* __restrict__ Wout, const float* __restrict__ W1,
               const float* __restrict__ W2, u16* __restrict__ ws)
{
  const int t = threadIdx.x;
  if (blockIdx.x >= 768) {
    int i = (blockIdx.x - 768) * 256 + t;
    if (i >= WS_WTOT) return;
    u16* wbase = ws + XT_ELEMS;
    int j = i;
    if (j < 4096)  { int n = j >> 5, k = j & 31;   wbase[WS_WQT   + j] = f2b(k < 16  ? Wq[k * 128 + n]  : 0.f); return; }
    j -= 4096;
    if (j < 40960) { int n = j / 160, k = j % 160; wbase[WS_WKVT  + j] = f2b(k < 144 ? Wkv[k * 256 + n] : 0.f); return; }
    j -= 40960;
    if (j < 2048)  { int n = j >> 7, k = j & 127;  wbase[WS_WOUTT + j] = f2b(Wout[k * 16 + n]); return; }
    j -= 2048;
    if (j < 1024)  { int n = j >> 5, k = j & 31;   wbase[WS_W1T   + j] = f2b(k < 16 ? W1[k * 32 + n] : 0.f); return; }
    j -= 1024;
    { int n = j >> 5, k = j & 31; wbase[WS_W2T + j] = f2b(W2[k * 16 + n]); }
    return;
  }
  __shared__ u16 buf[4096];
  const int node0 = blockIdx.x * 16;
  const int v = t >> 4, nd = t & 15;
  const f32x4* xp = (const f32x4*)(x + (size_t)v * XSTRIDE + (node0 + nd) * 16);
  f32x4 p0 = xp[0], p1 = xp[1], p2 = xp[2], p3 = xp[3];
  float va[16] = {p0[0],p0[1],p0[2],p0[3], p1[0],p1[1],p1[2],p1[3],
                  p2[0],p2[1],p2[2],p2[3], p3[0],p3[1],p3[2],p3[3]};
  float s = 0.f, ss = 0.f;
  #pragma unroll
  for (int j = 0; j < 16; ++j) { s += va[j]; ss += va[j] * va[j]; }
  float mean = s * 0.0625f, rs = rsqrtf(ss * 0.0625f - mean * mean + 1e-5f);
  short8 o0, o1;
  #pragma unroll
  for (int j = 0; j < 8; ++j) {
    o0[j] = (short)f2b((va[j]     - mean) * rs * ln1s[j]     + ln1b[j]);
    o1[j] = (short)f2b((va[j + 8] - mean) * rs * ln1s[j + 8] + ln1b[j + 8]);
  }
  *(short8*)(buf + nd * 256 + v * 16)     = o0;
  *(short8*)(buf + nd * 256 + v * 16 + 8) = o1;
  __syncthreads();
  const short8* src = (const short8*)(buf + t * 16);
  short8* dst = (short8*)(ws + node0 * 256 + t * 16);
  dst[0] = src[0]; dst[1] = src[1];
}

// ---------- main fused kernel: one block per attention group ----------
__global__ __launch_bounds__(256, 3)
void mfa_main(const float* __restrict__ x, const int* __restrict__ adjc,
              const float* __restrict__ bkv, const float* __restrict__ bout,
              const float* __restrict__ gamma, const float* __restrict__ ln2s,
              const float* __restrict__ ln2b, const float* __restrict__ b1,
              const float* __restrict__ b2, const float* __restrict__ gmlp,
              const u16* __restrict__ ws, float* __restrict__ y)
{
  __shared__ __align__(16) unsigned char smem[LDS_TOTAL];
  const int t = threadIdx.x, g = blockIdx.x;
  const int w = t >> 6, lrow = t & 15, kgrp = (t >> 4) & 3, k0 = kgrp * 8;

  char* stage = (char*)smem;                             // [64 tok][336B] (phase A/B)
  char* kbuf  = (char*)(smem + KBUF_OFF);                // [64 tok][272B] (phase C)
  char* vtb   = (char*)(smem + VTB_OFF);                 // [128 dim][144B]
  char* qsl   = (char*)(smem + QSL_OFF + w * QSL_SLOT);  // wave slot: qp/P/O; h/hid overlay

  const u16* xt = ws;
  const u16* wb = ws + XT_ELEMS;
  const f32x4 z4 = {0.f, 0.f, 0.f, 0.f};
  const short8 z8 = {0,0,0,0,0,0,0,0};

  // Token labeling: tau = nd*16 + v.  Wave w owns node nd = w (tnode uniform).
  const int tnode = g * 4 + w;

  // ======== Phase A: issue loads early; qproj overlaps stage-load latency ========
  short8 qbx = (kgrp < 2) ? *(const short8*)(xt + tnode * 256 + lrow * 16 + k0) : z8;
  short8 wqA[8];
  #pragma unroll
  for (int ft = 0; ft < 8; ++ft)
    wqA[ft] = *(const short8*)(wb + WS_WQT + (ft * 16 + lrow) * 32 + k0);

  // stage jobs: slab s = k_nbr*4 + ni (s<36), lane-in-slab = (v, half)
  int srow[5], scolb[5]; bool szp[5]; short8 sv[5];
  #pragma unroll
  for (int p = 0; p < 5; ++p) {
    int j = p * 256 + t, s = j >> 5, half = j & 1, vv = (j & 31) >> 1;
    if (s < 36) {
      int k = s >> 2, ni = s & 3;
      int an = adjc[g * 36 + ni * 9 + k];
      srow[p] = ni * 16 + vv; scolb[p] = k * 32 + half * 16; szp[p] = false;
      sv[p] = *(const short8*)(xt + an * 256 + vv * 16 + half * 8);
    } else {
      int z = (s - 36) * 32 + (t & 31);
      srow[p] = z >> 1; scolb[p] = 288 + (z & 1) * 16; szp[p] = true; sv[p] = z8;
    }
  }

  // qproj (swapped): D(m=feat 4kgrp+r, n=token lrow) -> packed b64 into qsl rows
  #pragma unroll
  for (int ft = 0; ft < 8; ++ft) {
    f32x4 c = MFMA16(wqA[ft], qbx, z4);
    *(uint2*)(qsl + lrow * S_Q + 32 * ft + 8 * kgrp) =
        make_uint2(pk2(c[0], c[1]), pk2(c[2], c[3]));
  }
  // stage writes (vv-stride 336B = 21 slots: conflict-free)
  #pragma unroll
  for (int p = 0; p < 5; ++p)
    *(short8*)(stage + srow[p] * S_STAGE + scolb[p]) = sv[p];
  __syncthreads();   // BAR1: stage + qp visible

  // ======== Phase B: kvproj [64 tok][160K] -> k (swapped) + vT ========
  f32x4 acc[4][4];   // [c: 2 k-tiles + 2 v-tiles][mt: token tile]
  #pragma unroll
  for (int c = 0; c < 4; ++c)
    #pragma unroll
    for (int mt = 0; mt < 4; ++mt) acc[c][mt] = z4;
  const int ctk = 2 * w, ctv = 8 + 2 * w;
  #pragma unroll
  for (int kc = 0; kc < 5; ++kc) {
    short8 tf[4], wf[4];
    #pragma unroll
    for (int mt = 0; mt < 4; ++mt)
      tf[mt] = *(const short8*)(stage + (mt * 16 + lrow) * S_STAGE + kc * 64 + kgrp * 16);
    wf[0] = *(const short8*)(wb + WS_WKVT + ((ctk    ) * 16 + lrow) * 160 + kc * 32 + k0);
    wf[1] = *(const short8*)(wb + WS_WKVT + ((ctk + 1) * 16 + lrow) * 160 + kc * 32 + k0);
    wf[2] = *(const short8*)(wb + WS_WKVT + ((ctv    ) * 16 + lrow) * 160 + kc * 32 + k0);
    wf[3] = *(const short8*)(wb + WS_WKVT + ((ctv + 1) * 16 + lrow) * 160 + kc * 32 + k0);
    #pragma unroll
    for (int mt = 0; mt < 4; ++mt) {
      acc[0][mt] = MFMA16(wf[0], tf[mt], acc[0][mt]);   // k: D(m=ch, n=tok)
      acc[1][mt] = MFMA16(wf[1], tf[mt], acc[1][mt]);
      acc[2][mt] = MFMA16(tf[mt], wf[2], acc[2][mt]);   // v: D(m=tok, n=ch)
      acc[3][mt] = MFMA16(tf[mt], wf[3], acc[3][mt]);
    }
  }
  __syncthreads();   // BAR2: all stage reads done before k/vT overwrite
  #pragma unroll
  for (int c = 0; c < 2; ++c) {        // k-half: token rows, 4 consecutive ch packed
    const int ct = ctk + c;
    f32x4 bk = *(const f32x4*)(bkv + ct * 16 + 4 * kgrp);
    #pragma unroll
    for (int mt = 0; mt < 4; ++mt) {
      f32x4 a = acc[c][mt];
      *(uint2*)(kbuf + (mt * 16 + lrow) * S_K + 32 * ct + 8 * kgrp) =
          make_uint2(pk2(a[0] + bk[0], a[1] + bk[1]), pk2(a[2] + bk[2], a[3] + bk[3]));
    }
  }
  #pragma unroll
  for (int c = 0; c < 2; ++c) {        // v-half: dim rows, 4 consecutive tokens packed
    const int vc = (2 * w + c) * 16 + lrow;
    float bv = bkv[128 + vc];
    #pragma unroll
    for (int mt = 0; mt < 4; ++mt) {
      f32x4 a = acc[2 + c][mt];
      *(uint2*)(vtb + vc * S_VT + 32 * mt + 8 * kgrp) =
          make_uint2(pk2(a[0] + bv, a[1] + bv), pk2(a[2] + bv, a[3] + bv));
    }
  }
  __syncthreads();   // BAR3: k/vT visible

  // ======== Phase C: per-head S^T -> in-lane softmax -> PV (O^T), head pairs ========
  short8 qbh0 = *(const short8*)(qsl + lrow * S_Q +   0 + 16 * kgrp);
  short8 qbh1 = *(const short8*)(qsl + lrow * S_Q +  64 + 16 * kgrp);
  short8 qbh2 = z8, qbh3 = z8;
  f32x4 oacc[4][2];
  float invh[4];
  #pragma unroll
  for (int h = 0; h < 4; ++h) { oacc[h][0] = z4; oacc[h][1] = z4; }

  #pragma unroll
  for (int hp = 0; hp < 2; ++hp) {
    const int h0 = 2 * hp, h1 = h0 + 1;
    f32x4 s4a[4], s4b[4];
    #pragma unroll
    for (int mt = 0; mt < 4; ++mt) {
      short8 ka = *(const short8*)(kbuf + (mt * 16 + lrow) * S_K + 64 * h0 + 16 * kgrp);
      s4a[mt] = MFMA16(ka, hp ? qbh2 : qbh0, z4);   // D(m=kv, n=q)
    }
    #pragma unroll
    for (int mt = 0; mt < 4; ++mt) {
      short8 kb = *(const short8*)(kbuf + (mt * 16 + lrow) * S_K + 64 * h1 + 16 * kgrp);
      s4b[mt] = MFMA16(kb, hp ? qbh3 : qbh1, z4);
    }
    if (hp == 0) {   // prefetch Q for heads 2,3 before P overwrites qp rows
      qbh2 = *(const short8*)(qsl + lrow * S_Q + 128 + 16 * kgrp);
      qbh3 = *(const short8*)(qsl + lrow * S_Q + 192 + 16 * kgrp);
    }
    invh[h0] = softmax16(s4a);
    invh[h1] = softmax16(s4b);
    #pragma unroll
    for (int mt = 0; mt < 4; ++mt) {   // P (unnormalized) packed into qp rows
      *(uint2*)(qsl + lrow * S_Q +       32 * mt + 8 * kgrp) =
          make_uint2(pk2(s4a[mt][0], s4a[mt][1]), pk2(s4a[mt][2], s4a[mt][3]));
      *(uint2*)(qsl + lrow * S_Q + 128 + 32 * mt + 8 * kgrp) =
          make_uint2(pk2(s4b[mt][0], s4b[mt][1]), pk2(s4b[mt][2], s4b[mt][3]));
    }
    DS_FENCE();
    #pragma unroll
    for (int hh = 0; hh < 2; ++hh) {
      const int h = 2 * hp + hh;
      #pragma unroll
      for (int kc = 0; kc < 2; ++kc) {
        short8 pB = *(const short8*)(qsl + lrow * S_Q + 128 * hh + 64 * kc + 16 * kgrp);
        #pragma unroll
        for (int nt = 0; nt < 2; ++nt) {
          short8 vA = *(const short8*)(vtb + (h * 32 + nt * 16 + lrow) * S_VT + 64 * kc + 16 * kgrp);
          oacc[h][nt] = MFMA16(vA, pB, oacc[h][nt]);   // O^T: D(m=dim, n=q)
        }
      }
    }
  }

  // params + residual (latency hidden under O-pack/fence)
  f32x4 p_gam = *(const f32x4*)(gamma + 4 * kgrp);
  f32x4 p_bo  = *(const f32x4*)(bout  + 4 * kgrp);
  f32x4 p_l2s = *(const f32x4*)(ln2s  + 4 * kgrp);
  f32x4 p_l2b = *(const f32x4*)(ln2b  + 4 * kgrp);
  f32x4 p_b1a = *(const f32x4*)(b1 + 4 * kgrp);
  f32x4 p_b1b = *(const f32x4*)(b1 + 16 + 4 * kgrp);
  f32x4 p_b2  = *(const f32x4*)(b2   + 4 * kgrp);
  f32x4 p_gm2 = *(const f32x4*)(gmlp + 4 * kgrp);
  f32x4 xr = *(const f32x4*)(x + (size_t)lrow * XSTRIDE + tnode * 16 + 4 * kgrp);

  // O (normalized) -> qp rows, packed
  #pragma unroll
  for (int h = 0; h < 4; ++h) {
    float iv = invh[h];
    #pragma unroll
    for (int nt = 0; nt < 2; ++nt) {
      f32x4 a = oacc[h][nt];
      *(uint2*)(qsl + lrow * S_Q + 64 * h + 32 * nt + 8 * kgrp) =
          make_uint2(pk2(a[0] * iv, a[1] * iv), pk2(a[2] * iv, a[3] * iv));
    }
  }
  DS_FENCE();

  // ======== Phase D: outproj + LN2 + MLP (wave-local) ========
  f32x4 oc = z4;
  #pragma unroll
  for (int kc = 0; kc < 4; ++kc) {
    short8 oB = *(const short8*)(qsl + lrow * S_Q + 64 * kc + 16 * kgrp);
    short8 wo = *(const short8*)(wb + WS_WOUTT + lrow * 128 + kc * 32 + k0);
    oc = MFMA16(wo, oB, oc);   // D(m=ch, n=token)
  }
  float xov[4]; float s = 0.f, ss = 0.f;
  #pragma unroll
  for (int r = 0; r < 4; ++r) {
    xov[r] = xr[r] + p_gam[r] * (oc[r] + p_bo[r]);
    s += xov[r]; ss += xov[r] * xov[r];
  }
  s  += __shfl_xor(s, 16);  s  += __shfl_xor(s, 32);
  ss += __shfl_xor(ss, 16); ss += __shfl_xor(ss, 32);
  float mean = s * 0.0625f, rstd = rsqrtf(ss * 0.0625f - mean * mean + 1e-5f);
  float hv[4];
  #pragma unroll
  for (int r = 0; r < 4; ++r) hv[r] = (xov[r] - mean) * rstd * p_l2s[r] + p_l2b[r];
  // h [16 tok][32ch pad], stride 144, at slot offset 0 (O already consumed; DS in-order)
  *(uint2*)(qsl + lrow * S_VT + 8 * kgrp)      = make_uint2(pk2(hv[0], hv[1]), pk2(hv[2], hv[3]));
  *(uint2*)(qsl + lrow * S_VT + 32 + 8 * kgrp) = make_uint2(0u, 0u);   // K-pad ch 16..31
  DS_FENCE();
  short8 hB = *(const short8*)(qsl + lrow * S_VT + 16 * kgrp);
  float hid[8];
  #pragma unroll
  for (int ft = 0; ft < 2; ++ft) {
    short8 w1 = *(const short8*)(wb + WS_W1T + (ft * 16 + lrow) * 32 + k0);
    f32x4 hc = MFMA16(w1, hB, z4);    // D(m=hch, n=token)
    f32x4 bb = ft ? p_b1b : p_b1a;
    #pragma unroll
    for (int r = 0; r < 4; ++r) hid[ft * 4 + r] = gelu_fast(hc[r] + bb[r]);
  }
  *(uint2*)(qsl + 2304 + lrow * S_VT + 8 * kgrp)      = make_uint2(pk2(hid[0], hid[1]), pk2(hid[2], hid[3]));
  *(uint2*)(qsl + 2304 + lrow * S_VT + 32 + 8 * kgrp) = make_uint2(pk2(hid[4], hid[5]), pk2(hid[6], hid[7]));
  DS_FENCE();
  short8 hidB = *(const short8*)(qsl + 2304 + lrow * S_VT + 16 * kgrp);
  short8 w2 = *(const short8*)(wb + WS_W2T + lrow * 32 + k0);
  f32x4 mc = MFMA16(w2, hidB, z4);    // D(m=out-ch, n=token)
  f32x4 yv;
  #pragma unroll
  for (int r = 0; r < 4; ++r) yv[r] = xov[r] + p_gm2[r] * (mc[r] + p_b2[r]);
  *(f32x4*)(y + (size_t)lrow * XSTRIDE + tnode * 16 + 4 * kgrp) = yv;
}

extern "C" void kernel_launch(void* const* d_in, const int* in_sizes, int n_in,
                              void* d_out, int out_size, void* d_ws, size_t ws_size,
                              hipStream_t stream) {
  const float* x    = (const float*)d_in[0];
  const int*   adjc = (const int*)  d_in[1];
  const float* ln1s = (const float*)d_in[2];
  const float* ln1b = (const float*)d_in[3];
  const float* Wq   = (const float*)d_in[4];
  const float* Wkv  = (const float*)d_in[5];
  const float* bkv  = (const float*)d_in[6];
  const float* Wout = (const float*)d_in[7];
  const float* bout = (const float*)d_in[8];
  const float* gam  = (const float*)d_in[9];
  const float* ln2s = (const float*)d_in[10];
  const float* ln2b = (const float*)d_in[11];
  const float* W1   = (const float*)d_in[12];
  const float* b1   = (const float*)d_in[13];
  const float* W2   = (const float*)d_in[14];
  const float* b2   = (const float*)d_in[15];
  const float* gmlp = (const float*)d_in[16];
  float* y = (float*)d_out;
  u16* ws = (u16*)d_ws;
  if (ws_size < WS_BYTES) return;   // needs ~6.4 MB scratch

  ln1x_prep<<<958, 256, 0, stream>>>(x, ln1s, ln1b, Wq, Wkv, Wout, W1, W2, ws);
  mfa_main<<<NGRP, 256, 0, stream>>>(x, adjc, bkv, bout, gam, ln2s, ln2b,
                                     b1, b2, gmlp, ws, y);
}